// Round 3
// baseline (180.592 us; speedup 1.0000x reference)
//
#include <hip/hip_runtime.h>
#include <hip/hip_bf16.h>
#include <cstdint>

#define DEV __device__ __forceinline__

typedef __attribute__((ext_vector_type(8))) __bf16 bf16x8;
typedef __attribute__((ext_vector_type(4))) float floatx4;
typedef __attribute__((ext_vector_type(4))) short shortx4;
typedef __attribute__((ext_vector_type(8))) short shortx8;

// 0.125 (= dim_head^-0.5) * log2(e): fold scale AND base-2 conversion into Q.
constexpr float QSCALE = 0.18033688011112042f;

DEV unsigned short f2b(float f) {
  union { float f; unsigned u; } v; v.f = f;
  return (unsigned short)((v.u + 0x7fffu + ((v.u >> 16) & 1u)) >> 16);  // RTNE
}

#if defined(__has_builtin) && __has_builtin(__builtin_amdgcn_cvt_pk_bf16_f32)
DEV unsigned pk2(float a, float b) {
  typedef __attribute__((ext_vector_type(2))) __bf16 bf2;
  union { bf2 v; unsigned u; } u;
  u.v = __builtin_amdgcn_cvt_pk_bf16_f32(a, b);
  return u.u;
}
#else
DEV unsigned pk2(float a, float b) {
  return (unsigned)f2b(a) | ((unsigned)f2b(b) << 16);
}
#endif

#if defined(__has_builtin) && __has_builtin(__builtin_amdgcn_exp2f)
DEV float fexp2(float x) { return __builtin_amdgcn_exp2f(x); }
#else
DEV float fexp2(float x) { return exp2f(x); }
#endif

DEV floatx4 mfma16(bf16x8 a, bf16x8 b, floatx4 c) {
  return __builtin_amdgcn_mfma_f32_16x16x32_bf16(a, b, c, 0, 0, 0);
}

#define GLD_LDS16(gp, lp)                                                          \
  __builtin_amdgcn_global_load_lds(                                                \
      (const __attribute__((address_space(1))) void*)(gp),                         \
      (__attribute__((address_space(3))) void*)(lp), 16, 0, 0)

// ---------------------------------------------------------------- conversions
__global__ void cvt_f32_bf16(const float* __restrict__ in,
                             unsigned short* __restrict__ out, int n4) {
  int i = blockIdx.x * 256 + threadIdx.x;
  if (i >= n4) return;
  floatx4 f = ((const floatx4*)in)[i];
  shortx4 s;
  s[0] = (short)f2b(f[0]); s[1] = (short)f2b(f[1]);
  s[2] = (short)f2b(f[2]); s[3] = (short)f2b(f[3]);
  ((shortx4*)out)[i] = s;
}

// out[c][r] = bf16(in[r][c]);  R,C multiples of 32
__global__ void tcvt(const float* __restrict__ in, unsigned short* __restrict__ out,
                     int R, int C) {
  __shared__ float tile[32][33];
  int tx = threadIdx.x & 31, ty = threadIdx.x >> 5;
  int r0 = blockIdx.y * 32, c0 = blockIdx.x * 32;
#pragma unroll
  for (int i = 0; i < 4; i++) {
    int rr = ty + i * 8;
    tile[rr][tx] = in[(size_t)(r0 + rr) * C + c0 + tx];
  }
  __syncthreads();
#pragma unroll
  for (int i = 0; i < 4; i++) {
    int rr = ty + i * 8;
    out[(size_t)(c0 + rr) * R + r0 + tx] = f2b(tile[tx][rr]);
  }
}

// ---------------------------------------------------------------- GEMM (C = A * Bt^T)
// A [M][K] bf16 row-major, Bt [N][K] bf16 row-major. 128x128 tile, BK=32.
// MODE 0: QKV epilogue. q,k -> [bh][n][64] via LDS transpose (coalesced 16B
//   stores); v -> sigma-permuted V^T [bh][64][2048] via packed 8B reg stores
//   (permutation matches the attn kernel's in-lane P packing).
// MODE 1: fp32 + bias via LDS transpose (two 32KB halves).
template <int MODE>
__global__ __launch_bounds__(256, 2) void gemm_bt(
    const unsigned short* __restrict__ A, const unsigned short* __restrict__ Bt, int K,
    unsigned short* __restrict__ qg, unsigned short* __restrict__ kg,
    unsigned short* __restrict__ vtg, float* __restrict__ outF,
    const float* __restrict__ bias) {
  __shared__ __align__(16) unsigned short smem[128 * 136];  // 34816 B
  unsigned short* Xs = smem;
  unsigned short* Ws = smem + 4096;
  const int tid = threadIdx.x;
  const int lane = tid & 63, wid = tid >> 6;
  const int g = lane >> 4, r = lane & 15;
  const int m0 = blockIdx.y * 128, n0 = blockIdx.x * 128;
  const int wm = (wid & 1) * 64, wn = (wid >> 1) * 64;

  floatx4 acc[4][4] = {};

  const int c0i = tid, c1i = 256 + tid;
  const int row0 = c0i >> 2, kb0 = (c0i & 3) ^ ((row0 >> 1) & 3);
  const int row1 = c1i >> 2, kb1 = (c1i & 3) ^ ((row1 >> 1) & 3);
  const unsigned ldsOff0 = (unsigned)(wid * 64) * 16;
  const unsigned ldsOff1 = (unsigned)(256 + wid * 64) * 16;

  for (int kt = 0; kt < K; kt += 32) {
    GLD_LDS16(A + (size_t)(m0 + row0) * K + kt + kb0 * 8, (char*)Xs + ldsOff0);
    GLD_LDS16(A + (size_t)(m0 + row1) * K + kt + kb1 * 8, (char*)Xs + ldsOff1);
    GLD_LDS16(Bt + (size_t)(n0 + row0) * K + kt + kb0 * 8, (char*)Ws + ldsOff0);
    GLD_LDS16(Bt + (size_t)(n0 + row1) * K + kt + kb1 * 8, (char*)Ws + ldsOff1);
    __syncthreads();
    bf16x8 a[4], b[4];
#pragma unroll
    for (int t = 0; t < 4; t++) {
      int rowA = wm + t * 16 + r;
      a[t] = *(const bf16x8*)(Xs + rowA * 32 + (g ^ ((rowA >> 1) & 3)) * 8);
      int rowB = wn + t * 16 + r;
      b[t] = *(const bf16x8*)(Ws + rowB * 32 + (g ^ ((rowB >> 1) & 3)) * 8);
    }
#pragma unroll
    for (int mt = 0; mt < 4; mt++)
#pragma unroll
      for (int nt = 0; nt < 4; nt++)
        acc[mt][nt] = mfma16(a[mt], b[nt], acc[mt][nt]);
    __syncthreads();
  }

  if (MODE == 0) {
    const int which = blockIdx.x >> 2;  // 0=q 1=k 2=v (block-uniform)
    if (which == 2) {
      // V^T with sigma permutation, packed 8B stores along n (reg dim).
      const int tokbase = m0 + wm;              // 64-aligned tile of tokens
      const int bb = tokbase >> 11, nb = tokbase & 2047;
#pragma unroll
      for (int mt = 0; mt < 4; mt++) {
        const int s = (mt >> 1) * 32 + g * 8 + (mt & 1) * 4;
#pragma unroll
        for (int nt = 0; nt < 4; nt++) {
          int vcol = n0 + wn + nt * 16 + r - 1024;
          int h = vcol >> 6, d = vcol & 63;
          unsigned long long w =
              (unsigned long long)pk2(acc[mt][nt][0], acc[mt][nt][1]) |
              ((unsigned long long)pk2(acc[mt][nt][2], acc[mt][nt][3]) << 32);
          *(unsigned long long*)(vtg + ((size_t)(bb * 8 + h) * 64 + d) * 2048 +
                                 nb + s) = w;
        }
      }
    } else {
      const float sc = (which == 0) ? QSCALE : 1.f;
      unsigned short* dst = (which == 0) ? qg : kg;
#pragma unroll
      for (int mt = 0; mt < 4; mt++)
#pragma unroll
        for (int nt = 0; nt < 4; nt++) {
          int col = wn + nt * 16 + r;
#pragma unroll
          for (int e = 0; e < 4; e++) {
            int row = wm + mt * 16 + g * 4 + e;
            smem[row * 136 + col] = f2b(acc[mt][nt][e] * sc);
          }
        }
      __syncthreads();
#pragma unroll
      for (int it = 0; it < 8; it++) {
        int c = it * 256 + tid;
        int row = c >> 4, cc = c & 15;
        shortx8 v = *(const shortx8*)(smem + row * 136 + cc * 8);
        int gq = n0 + cc * 8;            // global qkv col (q:0-511, k:512-1023)
        int h = (gq >> 6) & 7, d0 = gq & 63;
        int tok = m0 + row, bb = tok >> 11, n = tok & 2047;
        *(shortx8*)(dst + ((size_t)(bb * 8 + h) * 2048 + n) * 64 + d0) = v;
      }
    }
  } else {
    // fp32 + bias, two 32KB halves through LDS
    float* ftile = (float*)smem;  // 64 x 132
#pragma unroll
    for (int half = 0; half < 2; half++) {
      if (half) __syncthreads();
#pragma unroll
      for (int mi = 0; mi < 2; mi++) {
        int mt = half * 2 + mi;
#pragma unroll
        for (int nt = 0; nt < 4; nt++)
#pragma unroll
          for (int e = 0; e < 4; e++) {
            int lr = (wm >> 1) + mi * 16 + g * 4 + e;  // 0..63
            ftile[lr * 132 + wn + nt * 16 + r] = acc[mt][nt][e];
          }
      }
      __syncthreads();
#pragma unroll
      for (int it = 0; it < 8; it++) {
        int c = it * 256 + tid;
        int lr = c >> 5, cc = c & 31;
        floatx4 v = *(const floatx4*)(ftile + lr * 132 + cc * 4);
        int col = n0 + cc * 4;
        v += *(const floatx4*)(bias + col);
        int rowt = (lr < 32) ? (half * 32 + lr) : (64 + half * 32 + (lr - 32));
        *(floatx4*)(outF + (size_t)(m0 + rowt) * 512 + col) = v;
      }
    }
  }
}

// ---------------------------------------------------------------- flash attention
// grid (8, 32): 256 blocks = 1/CU. 4 waves x 64 q rows each; full kv sweep per
// wave (no splits, no barriers, no LDS in the loop). K/V frags load directly
// global->reg (L1 serves the 4-wave redundancy). P transpose C->A layout is
// pure in-lane packing because V^T is stored sigma-permuted by the QKV GEMM.
__global__ __launch_bounds__(256, 1) void attn(
    const unsigned short* __restrict__ qg, const unsigned short* __restrict__ kg,
    const unsigned short* __restrict__ vtg, unsigned short* __restrict__ ao) {
  __shared__ __align__(16) unsigned short Os[4][64 * 72];
  const int tid = threadIdx.x, lane = tid & 63, wid = tid >> 6;
  const int g = lane >> 4, r = lane & 15;
  const int bh = blockIdx.y;
  const int qw = blockIdx.x * 256 + wid * 64;
  const size_t base = (size_t)bh * (2048 * 64);
  const unsigned short* Vb = vtg + base;  // [64][2048], sigma-permuted

  // Q fragments (B operand): lane r = q col, k = d
  bf16x8 bq[4][2];
#pragma unroll
  for (int nt = 0; nt < 4; nt++)
#pragma unroll
    for (int kc = 0; kc < 2; kc++)
      bq[nt][kc] = *(const bf16x8*)(qg + base + (size_t)(qw + nt * 16 + r) * 64 +
                                    kc * 32 + g * 8);

  bf16x8 vones;
#pragma unroll
  for (int i = 0; i < 8; i++) vones[i] = (__bf16)1.0f;

  floatx4 o[4][4] = {};   // [q-block][d-block], C layout (col=d, row=q)
  floatx4 lacc[4] = {};   // row-sums, same layout

  // prefetched K fragments for current iter
  bf16x8 ak[4][2];
#pragma unroll
  for (int mt = 0; mt < 4; mt++)
#pragma unroll
    for (int kc = 0; kc < 2; kc++)
      ak[mt][kc] = *(const bf16x8*)(kg + base + (size_t)(mt * 16 + r) * 64 +
                                    kc * 32 + g * 8);

  for (int n0 = 0; n0 < 2048; n0 += 64) {
    // V fragments for this iter (land during S^T compute)
    bf16x8 bv[4][2];
#pragma unroll
    for (int b = 0; b < 4; b++)
#pragma unroll
      for (int kc = 0; kc < 2; kc++)
        bv[b][kc] = *(const bf16x8*)(Vb + (size_t)(b * 16 + r) * 2048 + n0 +
                                     kc * 32 + g * 8);

    // S^T [kv 64][q 64]: col=q(r), row=kv(g*4+e + 16*mt)
    floatx4 st[4][4] = {};
#pragma unroll
    for (int kc = 0; kc < 2; kc++)
#pragma unroll
      for (int mt = 0; mt < 4; mt++)
#pragma unroll
        for (int nt = 0; nt < 4; nt++)
          st[mt][nt] = mfma16(ak[mt][kc], bq[nt][kc], st[mt][nt]);

    // prefetch next iter's K
    if (n0 + 64 < 2048) {
#pragma unroll
      for (int mt = 0; mt < 4; mt++)
#pragma unroll
        for (int kc = 0; kc < 2; kc++)
          ak[mt][kc] = *(const bf16x8*)(kg + base +
                                        (size_t)(n0 + 64 + mt * 16 + r) * 64 +
                                        kc * 32 + g * 8);
    }

    // p = exp2(s) (no-max softmax; |s| bounded ~9), in-lane pack to A-frags
    bf16x8 ap[4][2];
#pragma unroll
    for (int a = 0; a < 4; a++) {
      float p[4][4];
#pragma unroll
      for (int mt = 0; mt < 4; mt++)
#pragma unroll
        for (int e = 0; e < 4; e++) p[mt][e] = fexp2(st[mt][a][e]);
#pragma unroll
      for (int kc = 0; kc < 2; kc++) {
        union { unsigned u[4]; bf16x8 v; } w;
        w.u[0] = pk2(p[2 * kc][0], p[2 * kc][1]);
        w.u[1] = pk2(p[2 * kc][2], p[2 * kc][3]);
        w.u[2] = pk2(p[2 * kc + 1][0], p[2 * kc + 1][1]);
        w.u[3] = pk2(p[2 * kc + 1][2], p[2 * kc + 1][3]);
        ap[a][kc] = w.v;
      }
    }

    // O += P*V, l += P*1
#pragma unroll
    for (int kc = 0; kc < 2; kc++) {
#pragma unroll
      for (int a = 0; a < 4; a++) {
        lacc[a] = mfma16(ap[a][kc], vones, lacc[a]);
#pragma unroll
        for (int b = 0; b < 4; b++)
          o[a][b] = mfma16(ap[a][kc], bv[b][kc], o[a][b]);
      }
    }
  }

  // normalize, LDS transpose (per-wave region), coalesced store
#pragma unroll
  for (int a = 0; a < 4; a++) {
    floatx4 il;
#pragma unroll
    for (int e = 0; e < 4; e++) il[e] = 1.f / lacc[a][e];
#pragma unroll
    for (int b = 0; b < 4; b++)
#pragma unroll
      for (int e = 0; e < 4; e++)
        Os[wid][(a * 16 + g * 4 + e) * 72 + b * 16 + r] = f2b(o[a][b][e] * il[e]);
  }
  __syncthreads();
  const int bb = bh >> 3, h = bh & 7;
#pragma unroll
  for (int it = 0; it < 8; it++) {
    int c = it * 64 + lane;
    int row = c >> 3, cc = c & 7;
    shortx8 v = *(const shortx8*)(&Os[wid][row * 72 + cc * 8]);
    *(shortx8*)(ao + ((size_t)(bb * 2048 + qw + row)) * 512 + h * 64 + cc * 8) = v;
  }
}

// ---------------------------------------------------------------- launcher
extern "C" void kernel_launch(void* const* d_in, const int* in_sizes, int n_in,
                              void* d_out, int out_size, void* d_ws, size_t ws_size,
                              hipStream_t stream) {
  const float* x = (const float*)d_in[0];      // [4,2048,512]
  const float* w_qkv = (const float*)d_in[1];  // [512,1536]
  const float* w_out = (const float*)d_in[2];  // [512,512]
  const float* b_out = (const float*)d_in[3];  // [512]
  float* out = (float*)d_out;                  // [4,2048,512] fp32

  unsigned short* wsp = (unsigned short*)d_ws;
  unsigned short* xb = wsp;                            // 8192*512
  unsigned short* wqkvt = xb + (size_t)8192 * 512;     // 1536*512
  unsigned short* woutt = wqkvt + (size_t)1536 * 512;  // 512*512
  unsigned short* qg = woutt + (size_t)512 * 512;      // [bh][2048][64]
  unsigned short* kg = qg + (size_t)32 * 2048 * 64;    // [bh][2048][64]
  unsigned short* vtg = kg + (size_t)32 * 2048 * 64;   // [bh][64][2048] sigma-perm
  unsigned short* ao = vtg + (size_t)32 * 2048 * 64;   // [8192][512]

  cvt_f32_bf16<<<4096, 256, 0, stream>>>(x, xb, 8192 * 512 / 4);
  tcvt<<<dim3(48, 16), 256, 0, stream>>>(w_qkv, wqkvt, 512, 1536);
  tcvt<<<dim3(16, 16), 256, 0, stream>>>(w_out, woutt, 512, 512);
  gemm_bt<0><<<dim3(12, 64), 256, 0, stream>>>(xb, wqkvt, 512, qg, kg, vtg,
                                               nullptr, nullptr);
  attn<<<dim3(8, 32), 256, 0, stream>>>(qg, kg, vtg, ao);
  gemm_bt<1><<<dim3(4, 64), 256, 0, stream>>>(ao, woutt, 512, nullptr, nullptr,
                                              nullptr, out, b_out);
}

// Round 4
// 157.709 us; speedup vs baseline: 1.1451x; 1.1451x over previous
//
#include <hip/hip_runtime.h>
#include <hip/hip_bf16.h>
#include <cstdint>

#define DEV __device__ __forceinline__

typedef __attribute__((ext_vector_type(8))) __bf16 bf16x8;
typedef __attribute__((ext_vector_type(4))) float floatx4;
typedef __attribute__((ext_vector_type(4))) short shortx4;
typedef __attribute__((ext_vector_type(8))) short shortx8;

// 0.125 (= dim_head^-0.5) * log2(e): fold scale AND base-2 conversion into Q.
constexpr float QSCALE = 0.18033688011112042f;

DEV unsigned short f2b(float f) {
  union { float f; unsigned u; } v; v.f = f;
  return (unsigned short)((v.u + 0x7fffu + ((v.u >> 16) & 1u)) >> 16);  // RTNE
}

#if defined(__has_builtin) && __has_builtin(__builtin_amdgcn_cvt_pk_bf16_f32)
DEV unsigned pk2(float a, float b) {
  typedef __attribute__((ext_vector_type(2))) __bf16 bf2;
  union { bf2 v; unsigned u; } u;
  u.v = __builtin_amdgcn_cvt_pk_bf16_f32(a, b);
  return u.u;
}
#else
DEV unsigned pk2(float a, float b) {
  return (unsigned)f2b(a) | ((unsigned)f2b(b) << 16);
}
#endif

#if defined(__has_builtin) && __has_builtin(__builtin_amdgcn_exp2f)
DEV float fexp2(float x) { return __builtin_amdgcn_exp2f(x); }
#else
DEV float fexp2(float x) { return exp2f(x); }
#endif

DEV floatx4 mfma16(bf16x8 a, bf16x8 b, floatx4 c) {
  return __builtin_amdgcn_mfma_f32_16x16x32_bf16(a, b, c, 0, 0, 0);
}

#define GLD_LDS16(gp, lp)                                                          \
  __builtin_amdgcn_global_load_lds(                                                \
      (const __attribute__((address_space(1))) void*)(gp),                         \
      (__attribute__((address_space(3))) void*)(lp), 16, 0, 0)

// ---------------------------------------------------------------- conversions
__global__ void cvt_f32_bf16(const float* __restrict__ in,
                             unsigned short* __restrict__ out, int n4) {
  int i = blockIdx.x * 256 + threadIdx.x;
  if (i >= n4) return;
  floatx4 f = ((const floatx4*)in)[i];
  shortx4 s;
  s[0] = (short)f2b(f[0]); s[1] = (short)f2b(f[1]);
  s[2] = (short)f2b(f[2]); s[3] = (short)f2b(f[3]);
  ((shortx4*)out)[i] = s;
}

// out[c][r] = bf16(in[r][c]);  R,C multiples of 32
__global__ void tcvt(const float* __restrict__ in, unsigned short* __restrict__ out,
                     int R, int C) {
  __shared__ float tile[32][33];
  int tx = threadIdx.x & 31, ty = threadIdx.x >> 5;
  int r0 = blockIdx.y * 32, c0 = blockIdx.x * 32;
#pragma unroll
  for (int i = 0; i < 4; i++) {
    int rr = ty + i * 8;
    tile[rr][tx] = in[(size_t)(r0 + rr) * C + c0 + tx];
  }
  __syncthreads();
#pragma unroll
  for (int i = 0; i < 4; i++) {
    int rr = ty + i * 8;
    out[(size_t)(c0 + rr) * R + r0 + tx] = f2b(tile[tx][rr]);
  }
}

// ---------------------------------------------------------------- QKV GEMM
// C = A * Bt^T. A [8192][512], Bt [1536][512]. Tile 256x128, BK=32, dbuf.
// grid (12, 32) = 384 blocks -> all co-resident at 2 blocks/CU (no tail wave).
// Epilogue: q,k via LDS transpose (coalesced 16B stores); v -> sigma-permuted
// V^T [bh][64][2048] via packed 8B register stores.
__global__ __launch_bounds__(256, 2) void gemm_qkv(
    const unsigned short* __restrict__ A, const unsigned short* __restrict__ Bt,
    unsigned short* __restrict__ qg, unsigned short* __restrict__ kg,
    unsigned short* __restrict__ vtg) {
  __shared__ __align__(16) unsigned short smem[24576];  // 48KB
  // A bufs: [0,16384) shorts (2 x 8192); B bufs: [16384, 24576) (2 x 4096)
  const int tid = threadIdx.x;
  const int lane = tid & 63, wid = tid >> 6;
  const int g = lane >> 4, r = lane & 15;
  const int m0 = blockIdx.y * 256, n0 = blockIdx.x * 128;
  const int wm = (wid & 1) * 128, wn = (wid >> 1) * 64;
  const int K = 512;

  floatx4 acc[8][4] = {};

  // staging chunk math (16B chunks, 4 per row, XOR-swizzled slots)
  int rowA[4], kbA[4];
#pragma unroll
  for (int i = 0; i < 4; i++) {
    int c = i * 256 + tid;
    rowA[i] = c >> 2;
    kbA[i] = (c & 3) ^ ((rowA[i] >> 1) & 3);
  }

#define STAGE_QKV(kt, b)                                                         \
  {                                                                              \
    _Pragma("unroll") for (int i = 0; i < 4; i++)                                \
        GLD_LDS16(A + (size_t)(m0 + rowA[i]) * K + (kt) + kbA[i] * 8,            \
                  (char*)smem + (b)*16384 + i * 4096 + wid * 1024);              \
    _Pragma("unroll") for (int i = 0; i < 2; i++)                                \
        GLD_LDS16(Bt + (size_t)(n0 + rowA[i]) * K + (kt) + kbA[i] * 8,           \
                  (char*)smem + 32768 + (b)*8192 + i * 4096 + wid * 1024);       \
  }

  STAGE_QKV(0, 0)
  for (int it = 0; it < 16; it++) {
    const int buf = it & 1;
    __syncthreads();
    if (it + 1 < 16) STAGE_QKV((it + 1) * 32, buf ^ 1)
    const unsigned short* Xs = smem + buf * 8192;
    const unsigned short* Ws = smem + 16384 + buf * 4096;
    bf16x8 a[8], b[4];
#pragma unroll
    for (int t = 0; t < 8; t++) {
      int rw = wm + t * 16 + r;
      a[t] = *(const bf16x8*)(Xs + rw * 32 + (g ^ ((rw >> 1) & 3)) * 8);
    }
#pragma unroll
    for (int t = 0; t < 4; t++) {
      int rw = wn + t * 16 + r;
      b[t] = *(const bf16x8*)(Ws + rw * 32 + (g ^ ((rw >> 1) & 3)) * 8);
    }
#pragma unroll
    for (int mt = 0; mt < 8; mt++)
#pragma unroll
      for (int nt = 0; nt < 4; nt++)
        acc[mt][nt] = mfma16(a[mt], b[nt], acc[mt][nt]);
  }
#undef STAGE_QKV

  const int which = blockIdx.x >> 2;  // 0=q 1=k 2=v (block-uniform)
  if (which == 2) {
    // sigma-permuted V^T, packed 8B stores (no LDS, no sync needed)
    const int tokbase = m0 + wm;  // 128-aligned
    const int bb = tokbase >> 11, nbase = tokbase & 2047;
#pragma unroll
    for (int mt = 0; mt < 8; mt++) {
      const int m3 = mt & 3;
      const int s = (mt >> 2) * 64 + (m3 >> 1) * 32 + g * 8 + (m3 & 1) * 4;
#pragma unroll
      for (int nt = 0; nt < 4; nt++) {
        int vcol = n0 + wn + nt * 16 + r - 1024;
        int h = vcol >> 6, d = vcol & 63;
        unsigned long long w =
            (unsigned long long)pk2(acc[mt][nt][0], acc[mt][nt][1]) |
            ((unsigned long long)pk2(acc[mt][nt][2], acc[mt][nt][3]) << 32);
        *(unsigned long long*)(vtg + ((size_t)(bb * 8 + h) * 64 + d) * 2048 +
                               nbase + s) = w;
      }
    }
  } else {
    const float sc = (which == 0) ? QSCALE : 1.f;
    unsigned short* dst = (which == 0) ? qg : kg;
#pragma unroll
    for (int half = 0; half < 2; half++) {
      __syncthreads();
      if ((wid & 1) == half) {
#pragma unroll
        for (int mt = 0; mt < 8; mt++)
#pragma unroll
          for (int nt = 0; nt < 4; nt++) {
            int rl = mt * 16 + g * 4;
            int col = wn + nt * 16 + r;
#pragma unroll
            for (int e = 0; e < 4; e++)
              smem[(rl + e) * 136 + col] = f2b(acc[mt][nt][e] * sc);
          }
      }
      __syncthreads();
#pragma unroll
      for (int it = 0; it < 8; it++) {
        int c = it * 256 + tid;
        int row = c >> 4, cc = c & 15;
        shortx8 v = *(const shortx8*)(smem + row * 136 + cc * 8);
        int gq = n0 + cc * 8;
        int h = (gq >> 6) & 7, d0 = gq & 63;
        int tok = m0 + half * 128 + row, bb = tok >> 11, n = tok & 2047;
        *(shortx8*)(dst + ((size_t)(bb * 8 + h) * 2048 + n) * 64 + d0) = v;
      }
    }
  }
}

// ---------------------------------------------------------------- out GEMM
// C = A * Bt^T + bias. A [8192][512] bf16, Bt [512][512] bf16, out fp32.
// 128x128 tile, BK=32, double-buffered.
__global__ __launch_bounds__(256, 2) void gemm_out(
    const unsigned short* __restrict__ A, const unsigned short* __restrict__ Bt,
    float* __restrict__ outF, const float* __restrict__ bias) {
  __shared__ __align__(16) unsigned short smem[17408];  // 34816 B
  // A bufs [0,8192) shorts; B bufs [8192,16384)
  const int tid = threadIdx.x;
  const int lane = tid & 63, wid = tid >> 6;
  const int g = lane >> 4, r = lane & 15;
  const int m0 = blockIdx.y * 128, n0 = blockIdx.x * 128;
  const int wm = (wid & 1) * 64, wn = (wid >> 1) * 64;
  const int K = 512;

  floatx4 acc[4][4] = {};

  int rowA[2], kbA[2];
#pragma unroll
  for (int i = 0; i < 2; i++) {
    int c = i * 256 + tid;
    rowA[i] = c >> 2;
    kbA[i] = (c & 3) ^ ((rowA[i] >> 1) & 3);
  }

#define STAGE_OUT(kt, b)                                                         \
  {                                                                              \
    _Pragma("unroll") for (int i = 0; i < 2; i++) {                              \
      GLD_LDS16(A + (size_t)(m0 + rowA[i]) * K + (kt) + kbA[i] * 8,              \
                (char*)smem + (b)*8192 + i * 4096 + wid * 1024);                 \
      GLD_LDS16(Bt + (size_t)(n0 + rowA[i]) * K + (kt) + kbA[i] * 8,             \
                (char*)smem + 16384 + (b)*8192 + i * 4096 + wid * 1024);         \
    }                                                                            \
  }

  STAGE_OUT(0, 0)
  for (int it = 0; it < 16; it++) {
    const int buf = it & 1;
    __syncthreads();
    if (it + 1 < 16) STAGE_OUT((it + 1) * 32, buf ^ 1)
    const unsigned short* Xs = smem + buf * 4096;
    const unsigned short* Ws = smem + 8192 + buf * 4096;
    bf16x8 a[4], b[4];
#pragma unroll
    for (int t = 0; t < 4; t++) {
      int rw = wm + t * 16 + r;
      a[t] = *(const bf16x8*)(Xs + rw * 32 + (g ^ ((rw >> 1) & 3)) * 8);
      int rb = wn + t * 16 + r;
      b[t] = *(const bf16x8*)(Ws + rb * 32 + (g ^ ((rb >> 1) & 3)) * 8);
    }
#pragma unroll
    for (int mt = 0; mt < 4; mt++)
#pragma unroll
      for (int nt = 0; nt < 4; nt++)
        acc[mt][nt] = mfma16(a[mt], b[nt], acc[mt][nt]);
  }
#undef STAGE_OUT

  // fp32 + bias, two 32KB halves through LDS
  float* ftile = (float*)smem;  // 64 x 132
#pragma unroll
  for (int half = 0; half < 2; half++) {
    __syncthreads();
#pragma unroll
    for (int mi = 0; mi < 2; mi++) {
      int mt = half * 2 + mi;
#pragma unroll
      for (int nt = 0; nt < 4; nt++)
#pragma unroll
        for (int e = 0; e < 4; e++) {
          int lr = (wm >> 1) + mi * 16 + g * 4 + e;  // 0..63
          ftile[lr * 132 + wn + nt * 16 + r] = acc[mt][nt][e];
        }
    }
    __syncthreads();
#pragma unroll
    for (int it = 0; it < 8; it++) {
      int c = it * 256 + tid;
      int lr = c >> 5, cc = c & 31;
      floatx4 v = *(const floatx4*)(ftile + lr * 132 + cc * 4);
      int col = n0 + cc * 4;
      v += *(const floatx4*)(bias + col);
      int rowt = (lr < 32) ? (half * 32 + lr) : (64 + half * 32 + (lr - 32));
      *(floatx4*)(outF + (size_t)(m0 + rowt) * 512 + col) = v;
    }
  }
}

// ---------------------------------------------------------------- flash attention
// grid (16, 32) = 512 blocks (2/CU). 4 waves: wq = q-half (64 rows), wk = kv
// stream (two 64-kv tiles per 128-kv iter). K/V double-buffered in LDS via
// global_load_lds; ONE barrier per iter (stage for it+1 issued right after it,
// vmcnt drains at the next barrier). P stays in-register: no-max softmax,
// in-lane C->A packing (V^T is sigma-permuted), l via MFMA(P, ones).
__global__ __launch_bounds__(256, 2) void attn(
    const unsigned short* __restrict__ qg, const unsigned short* __restrict__ kg,
    const unsigned short* __restrict__ vtg, unsigned short* __restrict__ ao) {
  __shared__ __align__(16) char L[65536];
  unsigned short* Ksm = (unsigned short*)L;            // [buf][wk][64*64] 32KB
  unsigned short* Vtm = (unsigned short*)(L + 32768);  // [buf][wk][64*64] 32KB
  const int tid = threadIdx.x, lane = tid & 63, wid = tid >> 6;
  const int g = lane >> 4, r = lane & 15, r7 = r & 7;
  const int wq = wid & 1, wk = wid >> 1;
  const int bh = blockIdx.y;
  const int q0 = blockIdx.x * 128 + wq * 64;
  const size_t base = (size_t)bh * (2048 * 64);
  const int chunk = (lane & 7) ^ ((lane >> 3) & 7);  // staging src chunk
  const int srow = lane >> 3;

  // Q fragments (B operand): lane r = q col, k = d
  bf16x8 bq[4][2];
#pragma unroll
  for (int nt = 0; nt < 4; nt++)
#pragma unroll
    for (int kc = 0; kc < 2; kc++)
      bq[nt][kc] = *(const bf16x8*)(qg + base + (size_t)(q0 + nt * 16 + r) * 64 +
                                    kc * 32 + g * 8);

  bf16x8 vones;
#pragma unroll
  for (int i = 0; i < 8; i++) vones[i] = (__bf16)1.0f;

  floatx4 o[4][4] = {};   // [q-block][d-block], C layout (col=d, row=q)
  floatx4 lacc[4] = {};   // row sums

#define STAGE_ATTN(it, b)                                                        \
  {                                                                              \
    const int sn0 = (it)*128 + wk * 64;                                          \
    if (wq == 0) {                                                               \
      _Pragma("unroll") for (int j = 0; j < 8; j++)                              \
          GLD_LDS16(kg + base + (size_t)(sn0 + j * 8 + srow) * 64 + chunk * 8,   \
                    (char*)L + ((b)*2 + wk) * 8192 + j * 1024);                  \
    } else {                                                                     \
      _Pragma("unroll") for (int j = 0; j < 8; j++)                              \
          GLD_LDS16(vtg + base + (size_t)(j * 8 + srow) * 2048 + sn0 + chunk * 8,\
                    (char*)L + 32768 + ((b)*2 + wk) * 8192 + j * 1024);          \
    }                                                                            \
  }

  STAGE_ATTN(0, 0)
  for (int it = 0; it < 16; it++) {
    const int buf = it & 1;
    __syncthreads();
    if (it + 1 < 16) STAGE_ATTN(it + 1, buf ^ 1)
    const unsigned short* Kt = Ksm + (buf * 2 + wk) * 4096;
    const unsigned short* Vt = Vtm + (buf * 2 + wk) * 4096;

    // S^T [kv 64][q 64]: col=q(r), row=kv(g*4+e + 16*mt)
    floatx4 st[4][4] = {};
#pragma unroll
    for (int kc = 0; kc < 2; kc++)
#pragma unroll
      for (int mt = 0; mt < 4; mt++) {
        bf16x8 ak = *(const bf16x8*)(Kt + (mt * 16 + r) * 64 +
                                     ((kc * 4 + g) ^ r7) * 8);
#pragma unroll
        for (int nt = 0; nt < 4; nt++)
          st[mt][nt] = mfma16(ak, bq[nt][kc], st[mt][nt]);
      }

    // p = exp2(s) (no-max softmax; |s| bounded), in-lane pack to A-frags
    bf16x8 ap[4][2];
#pragma unroll
    for (int a = 0; a < 4; a++) {
      float p[4][4];
#pragma unroll
      for (int mt = 0; mt < 4; mt++)
#pragma unroll
        for (int e = 0; e < 4; e++) p[mt][e] = fexp2(st[mt][a][e]);
#pragma unroll
      for (int kc = 0; kc < 2; kc++) {
        union { unsigned u[4]; bf16x8 v; } w;
        w.u[0] = pk2(p[2 * kc][0], p[2 * kc][1]);
        w.u[1] = pk2(p[2 * kc][2], p[2 * kc][3]);
        w.u[2] = pk2(p[2 * kc + 1][0], p[2 * kc + 1][1]);
        w.u[3] = pk2(p[2 * kc + 1][2], p[2 * kc + 1][3]);
        ap[a][kc] = w.v;
      }
    }

    // O += P*V, l += P*1
#pragma unroll
    for (int kc = 0; kc < 2; kc++) {
      bf16x8 bv[4];
#pragma unroll
      for (int b = 0; b < 4; b++)
        bv[b] = *(const bf16x8*)(Vt + (b * 16 + r) * 64 +
                                 ((kc * 4 + g) ^ r7) * 8);
#pragma unroll
      for (int a = 0; a < 4; a++) {
        lacc[a] = mfma16(ap[a][kc], vones, lacc[a]);
#pragma unroll
        for (int b = 0; b < 4; b++)
          o[a][b] = mfma16(ap[a][kc], bv[b], o[a][b]);
      }
    }
  }
#undef STAGE_ATTN

  // combine the two kv streams (pure adds) through LDS overlays
  float* fP = (float*)L;            // [0,32768): o exchange
  float* fL = (float*)(L + 32768);  // [32768,40960): l exchange
  unsigned short* Osm = (unsigned short*)(L + 40960);  // [2][64*72] 18KB
  __syncthreads();
  if (wk == 1) {
#pragma unroll
    for (int a = 0; a < 4; a++) {
      *(floatx4*)&fL[wq * 1024 + a * 256 + lane * 4] = lacc[a];
#pragma unroll
      for (int b = 0; b < 4; b++)
        *(floatx4*)&fP[wq * 4096 + (a * 4 + b) * 256 + lane * 4] = o[a][b];
    }
  }
  __syncthreads();
  if (wk == 0) {
#pragma unroll
    for (int a = 0; a < 4; a++) {
      floatx4 lt = lacc[a] + *(floatx4*)&fL[wq * 1024 + a * 256 + lane * 4];
      floatx4 il;
#pragma unroll
      for (int e = 0; e < 4; e++) il[e] = 1.f / lt[e];
#pragma unroll
      for (int b = 0; b < 4; b++) {
        floatx4 oo = o[a][b] +
                     *(floatx4*)&fP[wq * 4096 + (a * 4 + b) * 256 + lane * 4];
#pragma unroll
        for (int e = 0; e < 4; e++)
          Osm[wq * 4608 + (a * 16 + g * 4 + e) * 72 + b * 16 + r] =
              f2b(oo[e] * il[e]);
      }
    }
  }
  __syncthreads();
  const int bb = bh >> 3, h = bh & 7;
#pragma unroll
  for (int it = 0; it < 4; it++) {
    int c = it * 256 + tid;
    int row = c >> 3, cc = c & 7;
    int wqi = row >> 6, r6 = row & 63;
    shortx8 v = *(const shortx8*)(Osm + wqi * 4608 + r6 * 72 + cc * 8);
    int tok = blockIdx.x * 128 + row;
    *(shortx8*)(ao + ((size_t)(bb * 2048 + tok)) * 512 + h * 64 + cc * 8) = v;
  }
}

// ---------------------------------------------------------------- launcher
extern "C" void kernel_launch(void* const* d_in, const int* in_sizes, int n_in,
                              void* d_out, int out_size, void* d_ws, size_t ws_size,
                              hipStream_t stream) {
  const float* x = (const float*)d_in[0];      // [4,2048,512]
  const float* w_qkv = (const float*)d_in[1];  // [512,1536]
  const float* w_out = (const float*)d_in[2];  // [512,512]
  const float* b_out = (const float*)d_in[3];  // [512]
  float* out = (float*)d_out;                  // [4,2048,512] fp32

  unsigned short* wsp = (unsigned short*)d_ws;
  unsigned short* xb = wsp;                            // 8192*512
  unsigned short* wqkvt = xb + (size_t)8192 * 512;     // 1536*512
  unsigned short* woutt = wqkvt + (size_t)1536 * 512;  // 512*512
  unsigned short* qg = woutt + (size_t)512 * 512;      // [bh][2048][64]
  unsigned short* kg = qg + (size_t)32 * 2048 * 64;    // [bh][2048][64]
  unsigned short* vtg = kg + (size_t)32 * 2048 * 64;   // [bh][64][2048] sigma-perm
  unsigned short* ao = vtg + (size_t)32 * 2048 * 64;   // [8192][512]

  cvt_f32_bf16<<<4096, 256, 0, stream>>>(x, xb, 8192 * 512 / 4);
  tcvt<<<dim3(48, 16), 256, 0, stream>>>(w_qkv, wqkvt, 512, 1536);
  tcvt<<<dim3(16, 16), 256, 0, stream>>>(w_out, woutt, 512, 512);
  gemm_qkv<<<dim3(12, 32), 256, 0, stream>>>(xb, wqkvt, qg, kg, vtg);
  attn<<<dim3(16, 32), 256, 0, stream>>>(qg, kg, vtg, ao);
  gemm_out<<<dim3(4, 64), 256, 0, stream>>>(ao, woutt, out, b_out);
}